// Round 7
// baseline (226.801 us; speedup 1.0000x reference)
//
#include <hip/hip_runtime.h>
#include <hip/hip_bf16.h>

#define N_NODES 20000
#define DIM 128
#define N_EDGES 500000
#define BATCH 16384
#define EPS 1e-6f
#define L2E 1.4426950408889634f

typedef _Float16 half8 __attribute__((ext_vector_type(8)));
typedef _Float16 half4_t __attribute__((ext_vector_type(4)));
typedef float f32x4 __attribute__((ext_vector_type(4)));

__device__ __forceinline__ float fast_sqrtf(float x) {
#if __has_builtin(__builtin_amdgcn_sqrtf)
    return __builtin_amdgcn_sqrtf(x);
#else
    return sqrtf(x);
#endif
}
__device__ __forceinline__ float fast_exp2f(float x) {
#if __has_builtin(__builtin_amdgcn_exp2f)
    return __builtin_amdgcn_exp2f(x);
#else
    return exp2f(x);
#endif
}

// ---- workspace layout (bytes) ----
#define OFF_PSH   33280            // A: gathered p_star rows fp16 (16384*128*2)
#define OFF_PPH   4227584
#define OFF_N2S   8421888
#define OFF_N2P   8487424
#define OFF_BPS   8552960          // L2E * beta_p_star gathered
#define OFF_BP    8618496          // L2E * beta_p gathered
#define OFF_P16   8684032          // full fp16 p (20000*128*2)
#define OFF_PS16  13804032         // full fp16 p_star
#define OFF_END   18924032

// Fused prep: 2 gathers (rows->fp16 + norms + L2E*beta), 2 flat fp16 converts,
// and d_out zero-init (main atomically accumulates into it).
__global__ __launch_bounds__(256) void prep_kernel(
    const float* __restrict__ p, const float* __restrict__ p_star,
    const float* __restrict__ beta_p, const float* __restrict__ beta_ps,
    const int* __restrict__ nodes_ps, const int* __restrict__ nodes_p,
    _Float16* __restrict__ Ah, float* __restrict__ n2A, float* __restrict__ bA2,
    _Float16* __restrict__ Bh, float* __restrict__ n2B, float* __restrict__ bB2,
    _Float16* __restrict__ p16, _Float16* __restrict__ ps16, int use16,
    float* __restrict__ out)
{
    const int bx = blockIdx.x;
    if (bx == 0 && threadIdx.x == 0) out[0] = 0.f;
    if (bx < 4096) {
        const int g = threadIdx.x & 31;
        const int r8 = threadIdx.x >> 5;
        const bool isA = bx < 2048;
        int row = (isA ? bx : bx - 2048) * 8 + r8;
        int id = isA ? nodes_ps[row] : nodes_p[row];
        const float* src = isA ? p_star : p;
        float4 v = ((const float4*)(src + (size_t)id * DIM))[g];
        half4_t o;
        o[0] = (_Float16)v.x; o[1] = (_Float16)v.y; o[2] = (_Float16)v.z; o[3] = (_Float16)v.w;
        _Float16* dst = isA ? Ah : Bh;
        *(half4_t*)(dst + (size_t)row * DIM + g * 4) = o;
        float nrm = v.x * v.x + v.y * v.y + v.z * v.z + v.w * v.w;
        #pragma unroll
        for (int m = 16; m >= 1; m >>= 1) nrm += __shfl_xor(nrm, m, 32);
        if (g == 0) {
            if (isA) { n2A[row] = nrm; bA2[row] = L2E * beta_ps[id]; }
            else     { n2B[row] = nrm; bB2[row] = L2E * beta_p[id]; }
        }
    } else if (use16) {
        // flat convert: 640000 float4 per table, 512 per block, 1250 blocks/table
        int b = bx - 4096;
        const bool isP = b < 1250;
        const float* src = isP ? p : p_star;
        _Float16* dst = isP ? p16 : ps16;
        int base = (isP ? b : b - 1250) * 512 + threadIdx.x;
        #pragma unroll
        for (int u = 0; u < 2; ++u) {
            int f4 = base + u * 256;
            float4 v = ((const float4*)src)[f4];
            half4_t o;
            o[0] = (_Float16)v.x; o[1] = (_Float16)v.y; o[2] = (_Float16)v.z; o[3] = (_Float16)v.w;
            ((half4_t*)dst)[f4] = o;
        }
    }
}

// Main: 8256 blocks of 512 threads. One 128x128 non-link tile (8 waves x 32x64
// subtile) + 64 fused link edges per block. K split into two 64-wide halves
// through a single 37 KB LDS buffer -> 4 blocks/CU.
__global__ __launch_bounds__(512, 4) void main_kernel(
    const _Float16* __restrict__ Ag, const _Float16* __restrict__ Bg,
    const float* __restrict__ n2A, const float* __restrict__ n2B,
    const float* __restrict__ bA2, const float* __restrict__ bB2,
    const int* __restrict__ edges,
    const float* __restrict__ beta_p, const float* __restrict__ beta_ps,
    const _Float16* __restrict__ p16, const _Float16* __restrict__ ps16,
    const float* __restrict__ pf, const float* __restrict__ psf, int use16,
    float* __restrict__ out)
{
    const int bx = blockIdx.x, by = blockIdx.y;   // grid (129, 64)
    int ti, tj;
    const int len = 128 - by;
    if (bx < len) { ti = by; tj = by + bx; }
    else          { ti = 127 - by; tj = 127 - (bx - len); }
    const int i0 = ti * 128, j0 = tj * 128;
    const int bid = by * 129 + bx;
    const bool diag = (ti == tj);

    __shared__ __align__(16) _Float16 As[128][72];   // 64 data + 8 pad halves
    __shared__ __align__(16) _Float16 Bs[128][72];
    __shared__ float smr[8];

    const int tid = threadIdx.x;
    const int lane = tid & 63;
    const int w = tid >> 6;       // 0..7
    const int wm = w & 3;         // 32-row quarter
    const int wn = w >> 2;        // 64-col half
    const int quad = lane >> 4;
    const int lr = lane & 15;

    // ---- link edges: issue loads first ----
    float lsum = 0.f;
    half8 ea[2], eb[2];
    float ebeta[2] = {0.f, 0.f};
    bool ev[2];
    #pragma unroll
    for (int t = 0; t < 2; ++t) {
        int e = bid * 64 + w * 8 + quad * 2 + t;
        ev[t] = (e < N_EDGES);
        if (ev[t]) {
            int e0 = edges[e];
            int e1 = edges[N_EDGES + e];
            if (use16) {
                ea[t] = *(const half8*)(p16 + (size_t)e0 * DIM + lr * 8);
                eb[t] = *(const half8*)(ps16 + (size_t)e1 * DIM + lr * 8);
                if (lr == 0) ebeta[t] = beta_ps[e0] + beta_p[e1];
            } else {
                const float* ar = pf + (size_t)e0 * DIM + lr * 8;
                const float* br = psf + (size_t)e1 * DIM + lr * 8;
                float s = 0.f;
                #pragma unroll
                for (int k = 0; k < 8; ++k) {
                    float d = ar[k] - br[k] + EPS;
                    s = fmaf(d, d, s);
                }
                #pragma unroll
                for (int m = 8; m >= 1; m >>= 1) s += __shfl_xor(s, m, 16);
                if (lr == 0) lsum -= (beta_ps[e0] + beta_p[e1]) - fast_sqrtf(s);
            }
        }
    }

    // ---- hoisted epilogue operands ----
    const int ilo = i0 + wm * 32, jlo = j0 + wn * 64;
    float4 n2i[2], bi[2];
    #pragma unroll
    for (int mi = 0; mi < 2; ++mi) {
        n2i[mi] = *(const float4*)&n2A[ilo + mi * 16 + quad * 4];
        bi[mi]  = *(const float4*)&bA2[ilo + mi * 16 + quad * 4];
    }
    float n2j[4], bj[4];
    #pragma unroll
    for (int ni = 0; ni < 4; ++ni) {
        n2j[ni] = n2B[jlo + ni * 16 + lr];
        bj[ni]  = bB2[jlo + ni * 16 + lr];
    }

    // wave class on diagonal tiles: 0=free (all j>i), 1=masked, 2=dead
    int cls = 0;
    if (diag) cls = (wn == 0) ? (wm >= 2 ? 2 : 1) : (wm >= 2 ? 1 : 0);

    f32x4 acc[2][4] = {};
    #pragma unroll
    for (int kh = 0; kh < 2; ++kh) {
        if (kh) __syncthreads();   // protect LDS before overwrite
        // stage half-K: 1024 16B chunks per array, 2 per thread per array
        #pragma unroll
        for (int c = tid; c < 1024; c += 512) {
            int row = c >> 3, col = (c & 7) * 8;
            *(uint4*)&As[row][col] = *(const uint4*)(Ag + (size_t)(i0 + row) * DIM + kh * 64 + col);
            *(uint4*)&Bs[row][col] = *(const uint4*)(Bg + (size_t)(j0 + row) * DIM + kh * 64 + col);
        }
        __syncthreads();
        if (cls != 2) {
            #pragma unroll
            for (int ks = 0; ks < 2; ++ks) {
                int koff = ks * 32 + quad * 8;
                half8 af[2], bf[4];
                #pragma unroll
                for (int u = 0; u < 2; ++u) af[u] = *(const half8*)&As[wm * 32 + u * 16 + lr][koff];
                #pragma unroll
                for (int v = 0; v < 4; ++v) bf[v] = *(const half8*)&Bs[wn * 64 + v * 16 + lr][koff];
                #pragma unroll
                for (int mi = 0; mi < 2; ++mi)
                    #pragma unroll
                    for (int ni = 0; ni < 4; ++ni)
                        acc[mi][ni] = __builtin_amdgcn_mfma_f32_16x16x32_f16(af[mi], bf[ni], acc[mi][ni], 0, 0, 0);
            }
        }
    }

    if (cls != 2) {
        // epilogue: C/D layout col=lane&15, row=quad*4+reg
        if (cls == 0) {
            #pragma unroll
            for (int mi = 0; mi < 2; ++mi)
                #pragma unroll
                for (int ni = 0; ni < 4; ++ni) {
                    f32x4 d = acc[mi][ni];
                    #pragma unroll
                    for (int r = 0; r < 4; ++r) {
                        float tt = ((const float*)&n2i[mi])[r] + n2j[ni];
                        float sq = fmaxf(fmaf(d[r], -2.f, tt), 0.f);
                        float arg = fmaf(fast_sqrtf(sq), -L2E, ((const float*)&bi[mi])[r] + bj[ni]);
                        lsum += fast_exp2f(arg);
                    }
                }
        } else {
            #pragma unroll
            for (int mi = 0; mi < 2; ++mi)
                #pragma unroll
                for (int ni = 0; ni < 4; ++ni) {
                    f32x4 d = acc[mi][ni];
                    #pragma unroll
                    for (int r = 0; r < 4; ++r) {
                        int ig = ilo + mi * 16 + quad * 4 + r;
                        int jg = jlo + ni * 16 + lr;
                        float tt = ((const float*)&n2i[mi])[r] + n2j[ni];
                        float sq = fmaxf(fmaf(d[r], -2.f, tt), 0.f);
                        float arg = fmaf(fast_sqrtf(sq), -L2E, ((const float*)&bi[mi])[r] + bj[ni]);
                        float ex = fast_exp2f(arg);
                        if (jg > ig) lsum += ex;
                    }
                }
        }
    }

    // ---- link math (fp16 path) ----
    if (use16) {
        #pragma unroll
        for (int t = 0; t < 2; ++t) {
            if (ev[t]) {
                float s = 0.f;
                #pragma unroll
                for (int k = 0; k < 8; ++k) {
                    float d = (float)ea[t][k] - (float)eb[t][k] + EPS;
                    s = fmaf(d, d, s);
                }
                #pragma unroll
                for (int m = 8; m >= 1; m >>= 1) s += __shfl_xor(s, m, 16);
                if (lr == 0) lsum -= ebeta[t] - fast_sqrtf(s);
            }
        }
    }

    #pragma unroll
    for (int m = 32; m >= 1; m >>= 1) lsum += __shfl_xor(lsum, m, 64);
    if (lane == 0) smr[w] = lsum;
    __syncthreads();
    if (tid == 0) {
        float t = 0.f;
        #pragma unroll
        for (int i = 0; i < 8; ++i) t += smr[i];
        atomicAdd(out, t);
    }
}

extern "C" void kernel_launch(void* const* d_in, const int* in_sizes, int n_in,
                              void* d_out, int out_size, void* d_ws, size_t ws_size,
                              hipStream_t stream) {
    const int* edges = (const int*)d_in[0];
    const int* nodes_p_star = (const int*)d_in[1];
    const int* nodes_p = (const int*)d_in[2];
    const float* beta_p = (const float*)d_in[3];
    const float* beta_p_star = (const float*)d_in[4];
    const float* p = (const float*)d_in[5];
    const float* p_star = (const float*)d_in[6];

    char* ws = (char*)d_ws;
    _Float16* psh = (_Float16*)(ws + OFF_PSH);
    _Float16* pph = (_Float16*)(ws + OFF_PPH);
    float* n2s = (float*)(ws + OFF_N2S);
    float* n2p = (float*)(ws + OFF_N2P);
    float* bps2 = (float*)(ws + OFF_BPS);
    float* bp2 = (float*)(ws + OFF_BP);
    _Float16* p16 = (_Float16*)(ws + OFF_P16);
    _Float16* ps16 = (_Float16*)(ws + OFF_PS16);

    const int use16 = (ws_size >= (size_t)OFF_END) ? 1 : 0;

    prep_kernel<<<6596, 256, 0, stream>>>(
        p, p_star, beta_p, beta_p_star, nodes_p_star, nodes_p,
        psh, n2s, bps2, pph, n2p, bp2, p16, ps16, use16, (float*)d_out);

    main_kernel<<<dim3(129, 64), 512, 0, stream>>>(
        psh, pph, n2s, n2p, bps2, bp2,
        edges, beta_p, beta_p_star, p16, ps16, p, p_star, use16,
        (float*)d_out);
}

// Round 9
// 197.320 us; speedup vs baseline: 1.1494x; 1.1494x over previous
//
#include <hip/hip_runtime.h>
#include <hip/hip_bf16.h>
#include <hip/hip_fp8.h>

#define N_NODES 20000
#define DIM 128
#define N_EDGES 500000
#define BATCH 16384
#define EPS 1e-6f
#define L2E 1.4426950408889634f

typedef float f32x4 __attribute__((ext_vector_type(4)));
typedef float f32x2 __attribute__((ext_vector_type(2)));
typedef long long i64_t;

__device__ __forceinline__ float fast_sqrtf(float x) {
#if __has_builtin(__builtin_amdgcn_sqrtf)
    return __builtin_amdgcn_sqrtf(x);
#else
    return sqrtf(x);
#endif
}
__device__ __forceinline__ float fast_exp2f(float x) {
#if __has_builtin(__builtin_amdgcn_exp2f)
    return __builtin_amdgcn_exp2f(x);
#else
    return exp2f(x);
#endif
}

// pack 4 fp32 -> 4 fp8 e4m3 (OCP on gfx950; HW cvt produces the MFMA-consumed format)
__device__ __forceinline__ unsigned pack4_fp8(float a, float b, float c, float d) {
#if __has_builtin(__builtin_amdgcn_cvt_pk_fp8_f32)
    unsigned v = 0;
    v = __builtin_amdgcn_cvt_pk_fp8_f32(a, b, v, false);
    v = __builtin_amdgcn_cvt_pk_fp8_f32(c, d, v, true);
    return v;
#else
    __hip_fp8_e4m3 x0(a), x1(b), x2(c), x3(d);
    return (unsigned)x0.__x | ((unsigned)x1.__x << 8) |
           ((unsigned)x2.__x << 16) | ((unsigned)x3.__x << 24);
#endif
}

// hi-word select must be an immediate constant for the builtin -> template param
template <bool HI>
__device__ __forceinline__ f32x2 unpack2_fp8(unsigned v) {
#if __has_builtin(__builtin_amdgcn_cvt_pk_f32_fp8)
    return __builtin_amdgcn_cvt_pk_f32_fp8((int)v, HI);
#else
    __hip_fp8_e4m3 t0, t1;
    t0.__x = (unsigned char)(HI ? (v >> 16) : v);
    t1.__x = (unsigned char)(HI ? (v >> 24) : (v >> 8));
    f32x2 r; r.x = (float)t0; r.y = (float)t1;
    return r;
#endif
}

// ---- workspace layout (bytes, 64B aligned) ----
#define OFF_A8   0                 // gathered p_star rows fp8 (16384*128)
#define OFF_B8   2097152           // gathered p rows fp8
#define OFF_N2S  4194304
#define OFF_N2P  4259840
#define OFF_BPS  4325376           // L2E * beta_p_star gathered
#define OFF_BP   4390912           // L2E * beta_p gathered
#define OFF_P8   4456448           // full fp8 p (20000*128)
#define OFF_PS8  7016448           // full fp8 p_star
#define OFF_END  9576448           // ~9.1 MB total

// Fused prep: 2 gathers (rows->fp8 + fp32 norms + L2E*beta), 2 full-table fp8
// converts, d_out zero-init.
__global__ __launch_bounds__(256) void prep_kernel(
    const float* __restrict__ p, const float* __restrict__ p_star,
    const float* __restrict__ beta_p, const float* __restrict__ beta_ps,
    const int* __restrict__ nodes_ps, const int* __restrict__ nodes_p,
    unsigned char* __restrict__ A8, float* __restrict__ n2A, float* __restrict__ bA2,
    unsigned char* __restrict__ B8, float* __restrict__ n2B, float* __restrict__ bB2,
    unsigned char* __restrict__ p8, unsigned char* __restrict__ ps8,
    float* __restrict__ out)
{
    const int bx = blockIdx.x;
    if (bx == 0 && threadIdx.x == 0) out[0] = 0.f;
    if (bx < 4096) {
        const int g = threadIdx.x & 31;
        const int r8 = threadIdx.x >> 5;
        const bool isA = bx < 2048;
        int row = (isA ? bx : bx - 2048) * 8 + r8;
        int id = isA ? nodes_ps[row] : nodes_p[row];
        const float* src = isA ? p_star : p;
        float4 v = ((const float4*)(src + (size_t)id * DIM))[g];
        unsigned pk = pack4_fp8(v.x, v.y, v.z, v.w);
        unsigned char* dst = isA ? A8 : B8;
        ((unsigned*)(dst + (size_t)row * DIM))[g] = pk;
        float nrm = v.x * v.x + v.y * v.y + v.z * v.z + v.w * v.w;
        #pragma unroll
        for (int m = 16; m >= 1; m >>= 1) nrm += __shfl_xor(nrm, m, 32);
        if (g == 0) {
            if (isA) { n2A[row] = nrm; bA2[row] = L2E * beta_ps[id]; }
            else     { n2B[row] = nrm; bB2[row] = L2E * beta_p[id]; }
        }
    } else {
        // full-table convert: 640000 float4 per table, 512 per block
        int b = bx - 4096;
        const bool isP = b < 1250;
        const float* src = isP ? p : p_star;
        unsigned char* dst = isP ? p8 : ps8;
        int base = (isP ? b : b - 1250) * 512 + threadIdx.x;
        #pragma unroll
        for (int u = 0; u < 2; ++u) {
            int f4 = base + u * 256;
            float4 v = ((const float4*)src)[f4];
            ((unsigned*)dst)[f4] = pack4_fp8(v.x, v.y, v.z, v.w);
        }
    }
}

// Main: 8256 blocks x 512 threads. One 128x128 fp8 tile (8 waves, 32x64 each)
// + 64 fused link edges per block. Single full-K staging, one barrier,
// 37 KB LDS -> 4 blocks/CU.
#define LSTRIDE 144   // 128 data + 16 pad bytes: 16B-aligned rows
__global__ __launch_bounds__(512, 4) void main_kernel(
    const unsigned char* __restrict__ Ag, const unsigned char* __restrict__ Bg,
    const float* __restrict__ n2A, const float* __restrict__ n2B,
    const float* __restrict__ bA2, const float* __restrict__ bB2,
    const int* __restrict__ edges,
    const float* __restrict__ beta_p, const float* __restrict__ beta_ps,
    const unsigned char* __restrict__ p8, const unsigned char* __restrict__ ps8,
    float* __restrict__ out)
{
    const int bx = blockIdx.x, by = blockIdx.y;   // grid (129, 64)
    int ti, tj;
    const int len = 128 - by;
    if (bx < len) { ti = by; tj = by + bx; }
    else          { ti = 127 - by; tj = 127 - (bx - len); }
    const int i0 = ti * 128, j0 = tj * 128;
    const int bid = by * 129 + bx;
    const bool diag = (ti == tj);

    __shared__ __align__(16) unsigned char As[128 * LSTRIDE];
    __shared__ __align__(16) unsigned char Bs[128 * LSTRIDE];
    __shared__ float smr[8];

    const int tid = threadIdx.x;
    const int lane = tid & 63;
    const int w = tid >> 6;       // 0..7
    const int wm = w & 3;         // 32-row quarter
    const int wn = w >> 2;        // 64-col half
    const int quad = lane >> 4;
    const int lr = lane & 15;

    // ---- link edges: issue loads first (8 lanes/edge, 16B each) ----
    float lsum = 0.f;
    const int le = bid * 64 + w * 8 + (lane >> 3);
    const int lch = lane & 7;
    const bool ev = (le < N_EDGES);
    uint4 ua, ub;
    float ebeta = 0.f;
    if (ev) {
        int e0 = edges[le];
        int e1 = edges[N_EDGES + le];
        ua = *(const uint4*)(p8 + (size_t)e0 * DIM + lch * 16);
        ub = *(const uint4*)(ps8 + (size_t)e1 * DIM + lch * 16);
        if (lch == 0) ebeta = beta_ps[e0] + beta_p[e1];
    }

    // ---- hoisted epilogue operands ----
    const int ilo = i0 + wm * 32, jlo = j0 + wn * 64;
    float4 n2i[2], bi[2];
    #pragma unroll
    for (int mi = 0; mi < 2; ++mi) {
        n2i[mi] = *(const float4*)&n2A[ilo + mi * 16 + quad * 4];
        bi[mi]  = *(const float4*)&bA2[ilo + mi * 16 + quad * 4];
    }
    float n2j[4], bj[4];
    #pragma unroll
    for (int ni = 0; ni < 4; ++ni) {
        n2j[ni] = n2B[jlo + ni * 16 + lr];
        bj[ni]  = bB2[jlo + ni * 16 + lr];
    }

    // ---- stage both fp8 tiles: 1024 16B chunks per array, 2/thread/array ----
    #pragma unroll
    for (int c = tid; c < 1024; c += 512) {
        int row = c >> 3, col = (c & 7) * 16;
        *(uint4*)&As[row * LSTRIDE + col] = *(const uint4*)(Ag + (size_t)(i0 + row) * DIM + col);
        *(uint4*)&Bs[row * LSTRIDE + col] = *(const uint4*)(Bg + (size_t)(j0 + row) * DIM + col);
    }
    __syncthreads();

    // wave class on diagonal tiles: 0=free (all j>i), 1=masked, 2=dead
    int cls = 0;
    if (diag) cls = (wn == 0) ? (wm >= 2 ? 2 : 1) : (wm >= 2 ? 1 : 0);

    if (cls != 2) {
        f32x4 acc[2][4] = {};
        #pragma unroll
        for (int ks = 0; ks < 4; ++ks) {
            int koff = ks * 32 + quad * 8;
            i64_t af[2], bf[4];
            #pragma unroll
            for (int u = 0; u < 2; ++u)
                af[u] = *(const i64_t*)&As[(wm * 32 + u * 16 + lr) * LSTRIDE + koff];
            #pragma unroll
            for (int v = 0; v < 4; ++v)
                bf[v] = *(const i64_t*)&Bs[(wn * 64 + v * 16 + lr) * LSTRIDE + koff];
            #pragma unroll
            for (int mi = 0; mi < 2; ++mi)
                #pragma unroll
                for (int ni = 0; ni < 4; ++ni)
                    acc[mi][ni] = __builtin_amdgcn_mfma_f32_16x16x32_fp8_fp8(af[mi], bf[ni], acc[mi][ni], 0, 0, 0);
        }

        // epilogue: C/D layout col=lane&15, row=quad*4+reg (shape-determined)
        if (cls == 0) {
            #pragma unroll
            for (int mi = 0; mi < 2; ++mi)
                #pragma unroll
                for (int ni = 0; ni < 4; ++ni) {
                    f32x4 d = acc[mi][ni];
                    #pragma unroll
                    for (int r = 0; r < 4; ++r) {
                        float tt = ((const float*)&n2i[mi])[r] + n2j[ni];
                        float sq = fmaxf(fmaf(d[r], -2.f, tt), 0.f);
                        float arg = fmaf(fast_sqrtf(sq), -L2E, ((const float*)&bi[mi])[r] + bj[ni]);
                        lsum += fast_exp2f(arg);
                    }
                }
        } else {
            #pragma unroll
            for (int mi = 0; mi < 2; ++mi)
                #pragma unroll
                for (int ni = 0; ni < 4; ++ni) {
                    f32x4 d = acc[mi][ni];
                    #pragma unroll
                    for (int r = 0; r < 4; ++r) {
                        int ig = ilo + mi * 16 + quad * 4 + r;
                        int jg = jlo + ni * 16 + lr;
                        float tt = ((const float*)&n2i[mi])[r] + n2j[ni];
                        float sq = fmaxf(fmaf(d[r], -2.f, tt), 0.f);
                        float arg = fmaf(fast_sqrtf(sq), -L2E, ((const float*)&bi[mi])[r] + bj[ni]);
                        float ex = fast_exp2f(arg);
                        if (jg > ig) lsum += ex;
                    }
                }
        }
    }

    // ---- link math: fp8 data long since arrived ----
    if (ev) {
        float s = 0.f;
        #pragma unroll
        for (int d = 0; d < 4; ++d) {
            unsigned va = ((const unsigned*)&ua)[d];
            unsigned vb = ((const unsigned*)&ub)[d];
            f32x2 a0 = unpack2_fp8<false>(va), a1 = unpack2_fp8<true>(va);
            f32x2 b0 = unpack2_fp8<false>(vb), b1 = unpack2_fp8<true>(vb);
            float t0 = a0.x - b0.x + EPS, t1 = a0.y - b0.y + EPS;
            float t2 = a1.x - b1.x + EPS, t3 = a1.y - b1.y + EPS;
            s = fmaf(t0, t0, s); s = fmaf(t1, t1, s);
            s = fmaf(t2, t2, s); s = fmaf(t3, t3, s);
        }
        #pragma unroll
        for (int m = 4; m >= 1; m >>= 1) s += __shfl_xor(s, m, 8);
        if (lch == 0) lsum -= ebeta - fast_sqrtf(s);
    }

    #pragma unroll
    for (int m = 32; m >= 1; m >>= 1) lsum += __shfl_xor(lsum, m, 64);
    if (lane == 0) smr[w] = lsum;
    __syncthreads();
    if (tid == 0) {
        float t = 0.f;
        #pragma unroll
        for (int i = 0; i < 8; ++i) t += smr[i];
        atomicAdd(out, t);
    }
}

extern "C" void kernel_launch(void* const* d_in, const int* in_sizes, int n_in,
                              void* d_out, int out_size, void* d_ws, size_t ws_size,
                              hipStream_t stream) {
    const int* edges = (const int*)d_in[0];
    const int* nodes_p_star = (const int*)d_in[1];
    const int* nodes_p = (const int*)d_in[2];
    const float* beta_p = (const float*)d_in[3];
    const float* beta_p_star = (const float*)d_in[4];
    const float* p = (const float*)d_in[5];
    const float* p_star = (const float*)d_in[6];

    char* ws = (char*)d_ws;
    unsigned char* A8 = (unsigned char*)(ws + OFF_A8);
    unsigned char* B8 = (unsigned char*)(ws + OFF_B8);
    float* n2s = (float*)(ws + OFF_N2S);
    float* n2p = (float*)(ws + OFF_N2P);
    float* bps2 = (float*)(ws + OFF_BPS);
    float* bp2 = (float*)(ws + OFF_BP);
    unsigned char* p8 = (unsigned char*)(ws + OFF_P8);
    unsigned char* ps8 = (unsigned char*)(ws + OFF_PS8);

    prep_kernel<<<6596, 256, 0, stream>>>(
        p, p_star, beta_p, beta_p_star, nodes_p_star, nodes_p,
        A8, n2s, bps2, B8, n2p, bp2, p8, ps8, (float*)d_out);

    main_kernel<<<dim3(129, 64), 512, 0, stream>>>(
        A8, B8, n2s, n2p, bps2, bp2,
        edges, beta_p, beta_p_star, p8, ps8, (float*)d_out);
}